// Round 10
// baseline (5302.953 us; speedup 1.0000x reference)
//
#include <hip/hip_runtime.h>
#include <math.h>

#define LSEQ   4096
#define DMODEL 1024
#define NH     16
#define DHEAD  64
#define PSTRIDE 40  // P-buffer row stride in bf16: mult of 8 (b128 align)
// Finite mask: exp2(-30000) == 0 exactly; fully-masked half-tiles contribute
// p=0, l=0, O=0 -> trivially correct under the sum-merge (no NaN path).
#define MASKV  -30000.0f
#define C2SCALE 0.18033688f  // 0.125 * log2(e), folded into Q projection

typedef __attribute__((ext_vector_type(8))) short  bf16x8;
typedef __attribute__((ext_vector_type(4))) float  floatx4;
typedef unsigned short ushort_t;

#if __has_builtin(__builtin_amdgcn_exp2f)
#define EXP2F __builtin_amdgcn_exp2f
#else
#define EXP2F exp2f
#endif

__device__ __forceinline__ ushort_t f2bf(float x) {
  unsigned u = __builtin_bit_cast(unsigned, x);
  return (ushort_t)((u + 0x7fff + ((u >> 16) & 1)) >> 16);
}
__device__ __forceinline__ unsigned bf16pair(float a, float b) {
  return (unsigned)f2bf(a) | ((unsigned)f2bf(b) << 16);
}
// truncating pack: low16 = hi16(a), high16 = hi16(b) — 1 VALU (v_perm_b32)
__device__ __forceinline__ unsigned bfpack_trunc(float a, float b) {
  return __builtin_amdgcn_perm(__builtin_bit_cast(unsigned, b),
                               __builtin_bit_cast(unsigned, a), 0x07060302u);
}
__device__ __forceinline__ void gl_lds16(const ushort_t* g, ushort_t* l) {
  __builtin_amdgcn_global_load_lds(
      (const __attribute__((address_space(1))) void*)g,
      (__attribute__((address_space(3))) void*)l, 16, 0, 0);
}

// ---------------------------------------------------------------------------
// Exact RoPE table: rope[s][t] = {cos(s*invf_t), sin(s*invf_t)}, 4096x32.
// ---------------------------------------------------------------------------
__global__ void rope_table(float2* __restrict__ rope) {
  const int idx = blockIdx.x * 256 + threadIdx.x;  // 131072 total
  const int s = idx >> 5, t = idx & 31;
  const double invf = exp((double)t * -0.28782313662425572);  // -ln(10000)/32
  const double ang = (double)s * invf;
  rope[idx] = make_float2((float)cos(ang), (float)sin(ang));
}

// ---------------------------------------------------------------------------
// fp32 -> bf16 for [x | Wq | Wk | Wv | Wo] into one contiguous buffer.
// ---------------------------------------------------------------------------
__global__ void cvt_bf16(const float* __restrict__ x,  const float* __restrict__ wq,
                         const float* __restrict__ wk, const float* __restrict__ wv,
                         const float* __restrict__ wo, ushort_t* __restrict__ dst) {
  const size_t e = ((size_t)blockIdx.x * 256 + threadIdx.x) * 4;  // elem idx, 8M total
  const float* src; size_t off;
  if      (e < (size_t)(4u << 20)) { src = x;  off = e; }
  else if (e < (size_t)(5u << 20)) { src = wq; off = e - (size_t)(4u << 20); }
  else if (e < (size_t)(6u << 20)) { src = wk; off = e - (size_t)(5u << 20); }
  else if (e < (size_t)(7u << 20)) { src = wv; off = e - (size_t)(6u << 20); }
  else                             { src = wo; off = e - (size_t)(7u << 20); }
  const float4 v = *(const float4*)(src + off);
  uint2 p; p.x = bf16pair(v.x, v.y); p.y = bf16pair(v.z, v.w);
  *(uint2*)(dst + e) = p;
}

// ---------------------------------------------------------------------------
// m97-style bf16 MFMA GEMM (unchanged from R8).
// MODE 0: A=Om(bf16), B=Wo(bf16) -> fp32 C row-major (final projection)
// MODE 1: A=W fused QKV rows (3072xK), B=x. RoPE / V^T epilogues.
//         Q outputs are pre-scaled by C2SCALE (softmax fold).
// ---------------------------------------------------------------------------
template<int MODE>
__global__ __launch_bounds__(256)
void mfma_gemm(const ushort_t* __restrict__ A, const ushort_t* __restrict__ B,
               float* __restrict__ C, const float2* __restrict__ rope,
               ushort_t* __restrict__ Qo, ushort_t* __restrict__ Ko,
               ushort_t* __restrict__ Vo) {
  __shared__ ushort_t As[128 * 64];
  __shared__ ushort_t Bs[128 * 64];
  const int tid  = threadIdx.x;
  const int w    = tid >> 6, lane = tid & 63;
  const int wm   = w >> 1,   wn   = w & 1;
  const int quad = lane >> 4, col = lane & 15;
  const int i0 = blockIdx.x * 128;
  const int j0 = blockIdx.y * 128;

  const ushort_t* Ab = A + (size_t)i0 * DMODEL;
  const ushort_t* Bb = B + (size_t)j0 * DMODEL;

  floatx4 acc[4][4];
#pragma unroll
  for (int mt = 0; mt < 4; ++mt)
#pragma unroll
    for (int nt = 0; nt < 4; ++nt) acc[mt][nt] = (floatx4){0.f, 0.f, 0.f, 0.f};

  const int lrow = lane >> 3;
  const int lcol = (lane & 7) * 8;

  for (int k0 = 0; k0 < DMODEL; k0 += 64) {
    __syncthreads();
#pragma unroll
    for (int it = 0; it < 4; ++it) {
      const int rb = (it * 4 + w) * 8;
      gl_lds16(Ab + (size_t)(rb + lrow) * DMODEL + k0 + lcol, As + rb * 64);
      gl_lds16(Bb + (size_t)(rb + lrow) * DMODEL + k0 + lcol, Bs + rb * 64);
    }
    __syncthreads();

#pragma unroll
    for (int kk = 0; kk < 64; kk += 32) {
      bf16x8 af[4], bfr[4];
#pragma unroll
      for (int mt = 0; mt < 4; ++mt)
        af[mt] = *(const bf16x8*)(As + (wm * 64 + mt * 16 + col) * 64 + kk + quad * 8);
#pragma unroll
      for (int nt = 0; nt < 4; ++nt)
        bfr[nt] = *(const bf16x8*)(Bs + (wn * 64 + nt * 16 + col) * 64 + kk + quad * 8);
#pragma unroll
      for (int mt = 0; mt < 4; ++mt)
#pragma unroll
        for (int nt = 0; nt < 4; ++nt)
          acc[mt][nt] = __builtin_amdgcn_mfma_f32_16x16x32_bf16(
              af[mt], bfr[nt], acc[mt][nt], 0, 0, 0);
    }
  }

  if (MODE == 0) {
#pragma unroll
    for (int mt = 0; mt < 4; ++mt) {
      const int i = i0 + wm * 64 + mt * 16 + quad * 4;
#pragma unroll
      for (int nt = 0; nt < 4; ++nt) {
        const int j = j0 + wn * 64 + nt * 16 + col;
#pragma unroll
        for (int r = 0; r < 4; ++r)
          C[(size_t)(i + r) * DMODEL + j] = acc[mt][nt][r];
      }
    }
  } else {
    const int which = i0 >> 10;               // 0=Q 1=K 2=V
#pragma unroll
    for (int mt = 0; mt < 4; ++mt) {
      const int f0 = i0 + wm * 64 + mt * 16 + quad * 4;
      const int h  = (f0 >> 6) & 15;
      const int d  = f0 & 63;
      if (which == 2) {
#pragma unroll
        for (int nt = 0; nt < 4; ++nt) {
          const int s = j0 + wn * 64 + nt * 16 + col;
#pragma unroll
          for (int r = 0; r < 4; ++r)
            Vo[(size_t)(h * DHEAD + d + r) * LSEQ + s] = f2bf(acc[mt][nt][r]);
        }
      } else {
        ushort_t* dst = which ? Ko : Qo;
        const float qs = which ? 1.0f : C2SCALE;  // fold softmax scale into Q
        const int t0 = d >> 1;
#pragma unroll
        for (int nt = 0; nt < 4; ++nt) {
          const int s = j0 + wn * 64 + nt * 16 + col;
          const float4 cst = *(const float4*)((const float*)rope + ((size_t)s << 6) + t0 * 2);
          ushort_t* ob = dst + ((size_t)h * LSEQ + s) * DHEAD;
          const float x1 = acc[mt][nt][0], x2 = acc[mt][nt][1];
          const float y1 = acc[mt][nt][2], y2 = acc[mt][nt][3];
          *(unsigned*)(ob + t0)      = bf16pair((x1 * cst.x - x2 * cst.y) * qs,
                                                (y1 * cst.z - y2 * cst.w) * qs);
          *(unsigned*)(ob + t0 + 32) = bf16pair((x1 * cst.y + x2 * cst.x) * qs,
                                                (y1 * cst.w + y2 * cst.z) * qs);
        }
      }
    }
  }
}

// ---------------------------------------------------------------------------
// MFMA flash attention v8 = R8 envelope + R9 software pipeline.
// 256 blocks x 512 thr (8 waves, 2 waves/SIMD, launch_bounds(512,2) ->
// VGPR cap 256: the ~150-reg working set FITS; R9's (256,4) forced 64 VGPR
// and spilled ~1.4 GB/dispatch).
// Waves w / w+4 share one 32-q unit, split each 64-key tile in half.
// Pipeline: iter kt issues ds_read of P(kt-1) before QK(kt); PV(kt-1) runs
// after exp2(kt); P write->read gap is a full iteration (LDS latency hidden).
// kf single-buffered (reloaded after QK consumes it), vf 2-slot.
// Fixed-reference softmax; per-lane l; sum-merge across halves.
// ---------------------------------------------------------------------------
__global__ __launch_bounds__(512, 2)
void attn_mfma(const ushort_t* __restrict__ Qh, const ushort_t* __restrict__ Kh,
               const ushort_t* __restrict__ Vt, ushort_t* __restrict__ Om) {
  const int h   = blockIdx.x;
  const int g   = blockIdx.y;
  const int tid = threadIdx.x;
  const int w    = tid >> 6;     // 0..7
  const int wl   = w & 3;        // q-unit slot
  const int half = w >> 2;       // 0 = keys [0,32) of each tile, 1 = [32,64)
  const int lane = tid & 63;
  const int quad = lane >> 4;
  const int col  = lane & 15;

  // LDS: per-wave 2-slot P buffers (8 x 2 x 32 x PSTRIDE bf16 = 40960 B),
  // time-shared with the O-merge buffer (128 x 68 fp32 = 34816 B).
  __shared__ __align__(16) char smem[40960];
  ushort_t* Ps   = (ushort_t*)smem;
  float*    Obuf = (float*)smem;
  __shared__ float lbuf[4][2][16];
  ushort_t* psw = Ps + w * (2 * 32 * PSTRIDE);

  for (int pass = 0; pass < 2; ++pass) {
    const int qb    = pass ? (31 - g) : g;
    const int qbase = qb * 128 + wl * 32;
    const int nkt   = 2 * qb + 1 + (wl >> 1);   // 64-key tiles for this unit

    // Q B-frags (pre-scaled by C2), resident for the key loop
    bf16x8 qf[2][2];
#pragma unroll
    for (int nq = 0; nq < 2; ++nq)
#pragma unroll
      for (int c = 0; c < 2; ++c)
        qf[nq][c] = *(const bf16x8*)(Qh +
            ((size_t)(h * LSEQ + qbase + nq * 16 + col)) * DHEAD + quad * 8 + c * 32);

    floatx4 ot[4][2];
#pragma unroll
    for (int md = 0; md < 4; ++md)
#pragma unroll
      for (int nq = 0; nq < 2; ++nq) ot[md][nq] = (floatx4){0.f, 0.f, 0.f, 0.f};
    float l_[2] = {0.f, 0.f};

    bf16x8 kf[2][2], vfb[2][4], pf[2];

    auto load_k = [&](int kt) {
      const int key0 = kt * 64 + half * 32;
#pragma unroll
      for (int mk = 0; mk < 2; ++mk)
#pragma unroll
        for (int c = 0; c < 2; ++c)
          kf[mk][c] = *(const bf16x8*)(Kh +
              ((size_t)(h * LSEQ + key0 + mk * 16 + col)) * DHEAD + quad * 8 + c * 32);
    };
    auto load_v = [&](int kt, int slot) {
      const int key0 = kt * 64 + half * 32;
#pragma unroll
      for (int md = 0; md < 4; ++md)
        vfb[slot][md] = *(const bf16x8*)(Vt +
            ((size_t)(h * DHEAD + md * 16 + col)) * LSEQ + key0 + quad * 8);
    };

    load_k(0);
    load_v(0, 0);

    for (int kt = 0; kt < nkt; ++kt) {
      // (1) issue ds_read of P(kt-1) early — latency hides under QK+exp2
      if (kt > 0) {
        ushort_t* rs = psw + ((kt - 1) & 1) * (32 * PSTRIDE);
#pragma unroll
        for (int nq = 0; nq < 2; ++nq)
          pf[nq] = *(const bf16x8*)(rs + (nq * 16 + col) * PSTRIDE + quad * 8);
      }

      // (2) S^T = K . (C2*Q)^T for tile kt
      floatx4 st[2][2];
#pragma unroll
      for (int mk = 0; mk < 2; ++mk)
#pragma unroll
        for (int nq = 0; nq < 2; ++nq) st[mk][nq] = (floatx4){0.f, 0.f, 0.f, 0.f};
#pragma unroll
      for (int mk = 0; mk < 2; ++mk)
#pragma unroll
        for (int c = 0; c < 2; ++c)
#pragma unroll
          for (int nq = 0; nq < 2; ++nq)
            st[mk][nq] = __builtin_amdgcn_mfma_f32_16x16x32_bf16(
                kf[mk][c], qf[nq][c], st[mk][nq], 0, 0, 0);

      // (3) reload kf for kt+1 (kf consumed by QK above)
      if (kt + 1 < nkt) load_k(kt + 1);

      // (4) diagonal mask (only the wave's last tile can cross the diagonal)
      if (kt == nkt - 1) {
        const int key0 = kt * 64 + half * 32;
#pragma unroll
        for (int mk = 0; mk < 2; ++mk) {
          const int keyb = key0 + mk * 16 + quad * 4;
#pragma unroll
          for (int nq = 0; nq < 2; ++nq) {
            const int q = qbase + nq * 16 + col;
#pragma unroll
            for (int r = 0; r < 4; ++r)
              if (keyb + r > q) st[mk][nq][r] = MASKV;
          }
        }
      }

      // (5) p = exp2(S); accumulate l per-lane
#pragma unroll
      for (int mk = 0; mk < 2; ++mk)
#pragma unroll
        for (int nq = 0; nq < 2; ++nq) {
#pragma unroll
          for (int r = 0; r < 4; ++r) st[mk][nq][r] = EXP2F(st[mk][nq][r]);
          l_[nq] += (st[mk][nq][0] + st[mk][nq][1]) + (st[mk][nq][2] + st[mk][nq][3]);
        }

      // (6) PV(kt-1): pf ready by now; vf from slot (kt-1)&1
      if (kt > 0) {
#pragma unroll
        for (int md = 0; md < 4; ++md)
#pragma unroll
          for (int nq = 0; nq < 2; ++nq)
            ot[md][nq] = __builtin_amdgcn_mfma_f32_16x16x32_bf16(
                vfb[(kt - 1) & 1][md], pf[nq], ot[md][nq], 0, 0, 0);
      }

      // (7) P(kt) -> LDS slot kt&1 (read next iteration)
      {
        ushort_t* ws = psw + (kt & 1) * (32 * PSTRIDE);
#pragma unroll
        for (int mk = 0; mk < 2; ++mk)
#pragma unroll
          for (int nq = 0; nq < 2; ++nq) {
            uint2 pk;
            pk.x = bfpack_trunc(st[mk][nq][0], st[mk][nq][1]);
            pk.y = bfpack_trunc(st[mk][nq][2], st[mk][nq][3]);
            *(uint2*)(ws + (nq * 16 + col) * PSTRIDE + mk * 16 + quad * 4) = pk;
          }
      }

      // (8) V for kt+1 into slot (kt+1)&1 (slot (kt-1)&1 just consumed)
      if (kt + 1 < nkt) load_v(kt + 1, (kt + 1) & 1);
    }

    // flush PV(nkt-1)
    {
      ushort_t* rs = psw + ((nkt - 1) & 1) * (32 * PSTRIDE);
#pragma unroll
      for (int nq = 0; nq < 2; ++nq)
        pf[nq] = *(const bf16x8*)(rs + (nq * 16 + col) * PSTRIDE + quad * 8);
#pragma unroll
      for (int md = 0; md < 4; ++md)
#pragma unroll
        for (int nq = 0; nq < 2; ++nq)
          ot[md][nq] = __builtin_amdgcn_mfma_f32_16x16x32_bf16(
              vfb[(nkt - 1) & 1][md], pf[nq], ot[md][nq], 0, 0, 0);
    }

    // one-time l reduction per pass
    float lr[2];
#pragma unroll
    for (int nq = 0; nq < 2; ++nq) {
      float ls = l_[nq];
      ls += __shfl_xor(ls, 16);
      ls += __shfl_xor(ls, 32);
      lr[nq] = ls;
    }

    __syncthreads();  // key loops done; P region free for merge reuse

    if (half == 1) {  // upper-half wave dumps partials
#pragma unroll
      for (int nq = 0; nq < 2; ++nq) {
        if (quad == 0) lbuf[wl][nq][col] = lr[nq];
#pragma unroll
        for (int md = 0; md < 4; ++md)
          *(float4*)(Obuf + ((wl * 2 + nq) * 16 + col) * 68 + md * 16 + quad * 4) =
              (float4){ot[md][nq][0], ot[md][nq][1], ot[md][nq][2], ot[md][nq][3]};
      }
    }
    __syncthreads();

    if (half == 0) {  // lower-half wave merges (plain sums) and writes Om
#pragma unroll
      for (int nq = 0; nq < 2; ++nq) {
        const float inv = 1.0f / (lr[nq] + lbuf[wl][nq][col]);
        const int q = qbase + nq * 16 + col;
#pragma unroll
        for (int md = 0; md < 4; ++md) {
          const float4 ob =
              *(const float4*)(Obuf + ((wl * 2 + nq) * 16 + col) * 68 + md * 16 + quad * 4);
          uint2 pk;
          pk.x = bf16pair((ot[md][nq][0] + ob.x) * inv, (ot[md][nq][1] + ob.y) * inv);
          pk.y = bf16pair((ot[md][nq][2] + ob.z) * inv, (ot[md][nq][3] + ob.w) * inv);
          *(uint2*)(Om + (size_t)q * DMODEL + h * DHEAD + md * 16 + quad * 4) = pk;
        }
      }
    }
    __syncthreads();  // protect smem reuse in next pass
  }
}

extern "C" void kernel_launch(void* const* d_in, const int* in_sizes, int n_in,
                              void* d_out, int out_size, void* d_ws, size_t ws_size,
                              hipStream_t stream) {
  const float* x  = (const float*)d_in[0];
  const float* Wq = (const float*)d_in[2];
  const float* Wk = (const float*)d_in[3];
  const float* Wv = (const float*)d_in[4];
  const float* Wo = (const float*)d_in[5];
  float* out = (float*)d_out;

  const size_t M1 = (size_t)1 << 20;
  ushort_t* xb  = (ushort_t*)d_ws;      // bf16 x          4M elems
  ushort_t* Wb  = xb  + 4 * M1;         // bf16 Wq|Wk|Wv   3M (contiguous)
  ushort_t* wob = Wb  + 3 * M1;         // bf16 Wo         1M
  ushort_t* Qh  = wob + 1 * M1;         // bf16 [H][L][DH] 4M (pre-scaled C2)
  ushort_t* Kh  = Qh  + 4 * M1;         // bf16 [H][L][DH] 4M
  ushort_t* Vt  = Kh  + 4 * M1;         // bf16 [H][DH][L] 4M
  ushort_t* Om  = Vt  + 4 * M1;         // bf16 [L][D]     4M
  float2*   rope = (float2*)(Om + 4 * M1);  // 4096x32 float2, 1 MB

  rope_table<<<512, 256, 0, stream>>>(rope);
  cvt_bf16<<<8192, 256, 0, stream>>>(x, Wq, Wk, Wv, Wo, xb);
  mfma_gemm<1><<<dim3(3072 / 128, LSEQ / 128), 256, 0, stream>>>(
      Wb, xb, nullptr, rope, Qh, Kh, Vt);
  attn_mfma<<<dim3(NH, 32), 512, 0, stream>>>(Qh, Kh, Vt, Om);
  mfma_gemm<0><<<dim3(LSEQ / 128, DMODEL / 128), 256, 0, stream>>>(
      Om, wob, out, nullptr, nullptr, nullptr, nullptr);
}

// Round 11
// 280.444 us; speedup vs baseline: 18.9092x; 18.9092x over previous
//
#include <hip/hip_runtime.h>
#include <math.h>

#define LSEQ   4096
#define DMODEL 1024
#define NH     16
#define DHEAD  64
#define PSTRIDE 40  // P-buffer row stride in bf16: mult of 8 (b128 align)
// Finite mask: exp2(-30000) == 0 exactly; below-diagonal tiles contribute
// p=0, l=0, O=0 -> trivially correct under the sum-merge (no NaN path).
#define MASKV  -30000.0f
#define C2SCALE 0.18033688f  // 0.125 * log2(e), folded into Q projection

typedef __attribute__((ext_vector_type(8))) short  bf16x8;
typedef __attribute__((ext_vector_type(4))) float  floatx4;
typedef unsigned short ushort_t;

#if __has_builtin(__builtin_amdgcn_exp2f)
#define EXP2F __builtin_amdgcn_exp2f
#else
#define EXP2F exp2f
#endif

__device__ __forceinline__ ushort_t f2bf(float x) {
  unsigned u = __builtin_bit_cast(unsigned, x);
  return (ushort_t)((u + 0x7fff + ((u >> 16) & 1)) >> 16);
}
__device__ __forceinline__ unsigned bf16pair(float a, float b) {
  return (unsigned)f2bf(a) | ((unsigned)f2bf(b) << 16);
}
// truncating pack: low16 = hi16(a), high16 = hi16(b) — 1 VALU (v_perm_b32)
__device__ __forceinline__ unsigned bfpack_trunc(float a, float b) {
  return __builtin_amdgcn_perm(__builtin_bit_cast(unsigned, b),
                               __builtin_bit_cast(unsigned, a), 0x07060302u);
}
__device__ __forceinline__ void gl_lds16(const ushort_t* g, ushort_t* l) {
  __builtin_amdgcn_global_load_lds(
      (const __attribute__((address_space(1))) void*)g,
      (__attribute__((address_space(3))) void*)l, 16, 0, 0);
}

// ---------------------------------------------------------------------------
// Exact RoPE table: rope[s][t] = {cos(s*invf_t), sin(s*invf_t)}, 4096x32.
// ---------------------------------------------------------------------------
__global__ void rope_table(float2* __restrict__ rope) {
  const int idx = blockIdx.x * 256 + threadIdx.x;  // 131072 total
  const int s = idx >> 5, t = idx & 31;
  const double invf = exp((double)t * -0.28782313662425572);  // -ln(10000)/32
  const double ang = (double)s * invf;
  rope[idx] = make_float2((float)cos(ang), (float)sin(ang));
}

// ---------------------------------------------------------------------------
// fp32 -> bf16 for [x | Wq | Wk | Wv | Wo] into one contiguous buffer.
// ---------------------------------------------------------------------------
__global__ void cvt_bf16(const float* __restrict__ x,  const float* __restrict__ wq,
                         const float* __restrict__ wk, const float* __restrict__ wv,
                         const float* __restrict__ wo, ushort_t* __restrict__ dst) {
  const size_t e = ((size_t)blockIdx.x * 256 + threadIdx.x) * 4;  // elem idx, 8M total
  const float* src; size_t off;
  if      (e < (size_t)(4u << 20)) { src = x;  off = e; }
  else if (e < (size_t)(5u << 20)) { src = wq; off = e - (size_t)(4u << 20); }
  else if (e < (size_t)(6u << 20)) { src = wk; off = e - (size_t)(5u << 20); }
  else if (e < (size_t)(7u << 20)) { src = wv; off = e - (size_t)(6u << 20); }
  else                             { src = wo; off = e - (size_t)(7u << 20); }
  const float4 v = *(const float4*)(src + off);
  uint2 p; p.x = bf16pair(v.x, v.y); p.y = bf16pair(v.z, v.w);
  *(uint2*)(dst + e) = p;
}

// ---------------------------------------------------------------------------
// m97-style bf16 MFMA GEMM (unchanged from R8).
// MODE 0: A=Om(bf16), B=Wo(bf16) -> fp32 C row-major (final projection)
// MODE 1: A=W fused QKV rows (3072xK), B=x. RoPE / V^T epilogues.
//         Q outputs are pre-scaled by C2SCALE (softmax fold).
// ---------------------------------------------------------------------------
template<int MODE>
__global__ __launch_bounds__(256)
void mfma_gemm(const ushort_t* __restrict__ A, const ushort_t* __restrict__ B,
               float* __restrict__ C, const float2* __restrict__ rope,
               ushort_t* __restrict__ Qo, ushort_t* __restrict__ Ko,
               ushort_t* __restrict__ Vo) {
  __shared__ ushort_t As[128 * 64];
  __shared__ ushort_t Bs[128 * 64];
  const int tid  = threadIdx.x;
  const int w    = tid >> 6, lane = tid & 63;
  const int wm   = w >> 1,   wn   = w & 1;
  const int quad = lane >> 4, col = lane & 15;
  const int i0 = blockIdx.x * 128;
  const int j0 = blockIdx.y * 128;

  const ushort_t* Ab = A + (size_t)i0 * DMODEL;
  const ushort_t* Bb = B + (size_t)j0 * DMODEL;

  floatx4 acc[4][4];
#pragma unroll
  for (int mt = 0; mt < 4; ++mt)
#pragma unroll
    for (int nt = 0; nt < 4; ++nt) acc[mt][nt] = (floatx4){0.f, 0.f, 0.f, 0.f};

  const int lrow = lane >> 3;
  const int lcol = (lane & 7) * 8;

  for (int k0 = 0; k0 < DMODEL; k0 += 64) {
    __syncthreads();
#pragma unroll
    for (int it = 0; it < 4; ++it) {
      const int rb = (it * 4 + w) * 8;
      gl_lds16(Ab + (size_t)(rb + lrow) * DMODEL + k0 + lcol, As + rb * 64);
      gl_lds16(Bb + (size_t)(rb + lrow) * DMODEL + k0 + lcol, Bs + rb * 64);
    }
    __syncthreads();

#pragma unroll
    for (int kk = 0; kk < 64; kk += 32) {
      bf16x8 af[4], bfr[4];
#pragma unroll
      for (int mt = 0; mt < 4; ++mt)
        af[mt] = *(const bf16x8*)(As + (wm * 64 + mt * 16 + col) * 64 + kk + quad * 8);
#pragma unroll
      for (int nt = 0; nt < 4; ++nt)
        bfr[nt] = *(const bf16x8*)(Bs + (wn * 64 + nt * 16 + col) * 64 + kk + quad * 8);
#pragma unroll
      for (int mt = 0; mt < 4; ++mt)
#pragma unroll
        for (int nt = 0; nt < 4; ++nt)
          acc[mt][nt] = __builtin_amdgcn_mfma_f32_16x16x32_bf16(
              af[mt], bfr[nt], acc[mt][nt], 0, 0, 0);
    }
  }

  if (MODE == 0) {
#pragma unroll
    for (int mt = 0; mt < 4; ++mt) {
      const int i = i0 + wm * 64 + mt * 16 + quad * 4;
#pragma unroll
      for (int nt = 0; nt < 4; ++nt) {
        const int j = j0 + wn * 64 + nt * 16 + col;
#pragma unroll
        for (int r = 0; r < 4; ++r)
          C[(size_t)(i + r) * DMODEL + j] = acc[mt][nt][r];
      }
    }
  } else {
    const int which = i0 >> 10;               // 0=Q 1=K 2=V
#pragma unroll
    for (int mt = 0; mt < 4; ++mt) {
      const int f0 = i0 + wm * 64 + mt * 16 + quad * 4;
      const int h  = (f0 >> 6) & 15;
      const int d  = f0 & 63;
      if (which == 2) {
#pragma unroll
        for (int nt = 0; nt < 4; ++nt) {
          const int s = j0 + wn * 64 + nt * 16 + col;
#pragma unroll
          for (int r = 0; r < 4; ++r)
            Vo[(size_t)(h * DHEAD + d + r) * LSEQ + s] = f2bf(acc[mt][nt][r]);
        }
      } else {
        ushort_t* dst = which ? Ko : Qo;
        const float qs = which ? 1.0f : C2SCALE;  // fold softmax scale into Q
        const int t0 = d >> 1;
#pragma unroll
        for (int nt = 0; nt < 4; ++nt) {
          const int s = j0 + wn * 64 + nt * 16 + col;
          const float4 cst = *(const float4*)((const float*)rope + ((size_t)s << 6) + t0 * 2);
          ushort_t* ob = dst + ((size_t)h * LSEQ + s) * DHEAD;
          const float x1 = acc[mt][nt][0], x2 = acc[mt][nt][1];
          const float y1 = acc[mt][nt][2], y2 = acc[mt][nt][3];
          *(unsigned*)(ob + t0)      = bf16pair((x1 * cst.x - x2 * cst.y) * qs,
                                                (y1 * cst.z - y2 * cst.w) * qs);
          *(unsigned*)(ob + t0 + 32) = bf16pair((x1 * cst.y + x2 * cst.x) * qs,
                                                (y1 * cst.w + y2 * cst.z) * qs);
        }
      }
    }
  }
}

// ---------------------------------------------------------------------------
// MFMA flash attention v9: block-level LDS staging of K/V tiles.
// R8 analysis: per-wave global K/V fragment loads = ~2.1 GB L2 traffic =
// ~62 us floor — THE binding constraint. Here each 64-key K-tile (8 KB) and
// V-tile (8 KB) is staged ONCE per block via global_load_lds (512 thr x 16 B,
// wave-uniform LDS bases), double-buffered, 1 barrier/tile; waves ds_read
// their fragments. 4x less L2 traffic, global latency out of the loop.
// All VGPR arrays statically indexed (R10 lesson: dynamic slot indices on
// register arrays -> private-memory lowering, 40x regression). Buffer select
// lives only in LDS address arithmetic (legal).
// Grid (16,16), 512 thr; 2-pass {g,31-g}; uniform nkt_max=2qb+2 for all
// waves (below-diagonal tiles fully mask to p=0 -> uniform barrier counts).
// Fixed-reference softmax; per-lane l; sum-merge across key halves.
// ---------------------------------------------------------------------------
__global__ __launch_bounds__(512, 2)
void attn_mfma(const ushort_t* __restrict__ Qh, const ushort_t* __restrict__ Kh,
               const ushort_t* __restrict__ Vt, ushort_t* __restrict__ Om) {
  const int h   = blockIdx.x;
  const int g   = blockIdx.y;
  const int tid = threadIdx.x;
  const int w    = tid >> 6;     // 0..7
  const int wl   = w & 3;        // q-unit slot (32 q rows each)
  const int half = w >> 2;       // 0 = keys [0,32) of each tile, 1 = [32,64)
  const int lane = tid & 63;
  const int quad = lane >> 4;
  const int col  = lane & 15;

  // LDS map (bytes): Ks dbuf [0,16384) | Vs dbuf [16384,32768) |
  //                  P per-wave [32768,53248). Obuf (merge, 34816 B) aliases
  //                  the staging region after the key loop.
  __shared__ __align__(16) char smem[53248];
  ushort_t* Ks   = (ushort_t*)smem;                  // [2][64*64]
  ushort_t* Vs   = (ushort_t*)(smem + 16384);        // [2][64*64]
  ushort_t* Ps   = (ushort_t*)(smem + 32768);        // [8][32*PSTRIDE]
  float*    Obuf = (float*)smem;
  __shared__ float lbuf[4][2][16];
  ushort_t* psw = Ps + w * (32 * PSTRIDE);

  // staging lane geometry: wave w stages rows [w*8, w*8+8), lane -> +lane*8
  const int srow = w * 8 + (lane >> 3);
  const int scol = (lane & 7) * 8;

  for (int pass = 0; pass < 2; ++pass) {
    const int qb      = pass ? (31 - g) : g;
    const int qbase   = qb * 128 + wl * 32;
    const int nkt_max = 2 * qb + 2;   // uniform across all waves

    // Q B-frags (pre-scaled by C2), resident for the key loop
    bf16x8 qf[2][2];
#pragma unroll
    for (int nq = 0; nq < 2; ++nq)
#pragma unroll
      for (int c = 0; c < 2; ++c)
        qf[nq][c] = *(const bf16x8*)(Qh +
            ((size_t)(h * LSEQ + qbase + nq * 16 + col)) * DHEAD + quad * 8 + c * 32);

    floatx4 ot[4][2];
#pragma unroll
    for (int md = 0; md < 4; ++md)
#pragma unroll
      for (int nq = 0; nq < 2; ++nq) ot[md][nq] = (floatx4){0.f, 0.f, 0.f, 0.f};
    float l_[2] = {0.f, 0.f};

    // stage tile kt into LDS buffer b (wave-uniform bases; lane*16B contiguous)
    auto stage = [&](int kt, int b) {
      const int key0 = kt * 64;
      gl_lds16(Kh + ((size_t)(h * LSEQ + key0 + srow)) * DHEAD + scol,
               Ks + b * 4096 + w * 512);
      gl_lds16(Vt + ((size_t)(h * DHEAD + srow)) * LSEQ + key0 + scol,
               Vs + b * 4096 + w * 512);
    };

    stage(0, 0);
    __syncthreads();  // staging 0 visible (barrier drains vmcnt)

    for (int kt = 0; kt < nkt_max; ++kt) {
      const int buf = kt & 1;
      if (kt + 1 < nkt_max) stage(kt + 1, buf ^ 1);  // fills other buffer

      const ushort_t* kb = Ks + buf * 4096;
      const ushort_t* vb = Vs + buf * 4096;

      // kf frags from LDS: keys [half*32 + mk*16 + col]
      bf16x8 kf[2][2];
#pragma unroll
      for (int mk = 0; mk < 2; ++mk)
#pragma unroll
        for (int c = 0; c < 2; ++c)
          kf[mk][c] = *(const bf16x8*)(kb + (half * 32 + mk * 16 + col) * 64 +
                                       c * 32 + quad * 8);

      // S^T = K . (C2*Q)^T  (32 keys x 32 q)
      floatx4 st[2][2];
#pragma unroll
      for (int mk = 0; mk < 2; ++mk)
#pragma unroll
        for (int nq = 0; nq < 2; ++nq) st[mk][nq] = (floatx4){0.f, 0.f, 0.f, 0.f};
#pragma unroll
      for (int mk = 0; mk < 2; ++mk)
#pragma unroll
        for (int c = 0; c < 2; ++c)
#pragma unroll
          for (int nq = 0; nq < 2; ++nq)
            st[mk][nq] = __builtin_amdgcn_mfma_f32_16x16x32_bf16(
                kf[mk][c], qf[nq][c], st[mk][nq], 0, 0, 0);

      // mask near/beyond the diagonal (absolute indices; below-diag = no-op,
      // beyond-diag tiles mask everything -> p=0)
      if (kt >= nkt_max - 2) {
        const int key0 = kt * 64 + half * 32;
#pragma unroll
        for (int mk = 0; mk < 2; ++mk) {
          const int keyb = key0 + mk * 16 + quad * 4;
#pragma unroll
          for (int nq = 0; nq < 2; ++nq) {
            const int q = qbase + nq * 16 + col;
#pragma unroll
            for (int r = 0; r < 4; ++r)
              if (keyb + r > q) st[mk][nq][r] = MASKV;
          }
        }
      }

      // p = exp2(S); accumulate l per-lane
#pragma unroll
      for (int mk = 0; mk < 2; ++mk)
#pragma unroll
        for (int nq = 0; nq < 2; ++nq) {
#pragma unroll
          for (int r = 0; r < 4; ++r) st[mk][nq][r] = EXP2F(st[mk][nq][r]);
          l_[nq] += (st[mk][nq][0] + st[mk][nq][1]) + (st[mk][nq][2] + st[mk][nq][3]);
        }

      // P^T -> per-wave LDS (truncating pack), then P B-frags
#pragma unroll
      for (int mk = 0; mk < 2; ++mk)
#pragma unroll
        for (int nq = 0; nq < 2; ++nq) {
          uint2 pk;
          pk.x = bfpack_trunc(st[mk][nq][0], st[mk][nq][1]);
          pk.y = bfpack_trunc(st[mk][nq][2], st[mk][nq][3]);
          *(uint2*)(psw + (nq * 16 + col) * PSTRIDE + mk * 16 + quad * 4) = pk;
        }
      bf16x8 pf[2];
#pragma unroll
      for (int nq = 0; nq < 2; ++nq)
        pf[nq] = *(const bf16x8*)(psw + (nq * 16 + col) * PSTRIDE + quad * 8);

      // vf frags from LDS; O^T += V^T . P^T
      bf16x8 vf[4];
#pragma unroll
      for (int md = 0; md < 4; ++md)
        vf[md] = *(const bf16x8*)(vb + (md * 16 + col) * 64 + half * 32 + quad * 8);
#pragma unroll
      for (int md = 0; md < 4; ++md)
#pragma unroll
        for (int nq = 0; nq < 2; ++nq)
          ot[md][nq] = __builtin_amdgcn_mfma_f32_16x16x32_bf16(
              vf[md], pf[nq], ot[md][nq], 0, 0, 0);

      __syncthreads();  // staging kt+1 done; all reads of buf kt finished
    }

    // one-time l reduction per pass
    float lr[2];
#pragma unroll
    for (int nq = 0; nq < 2; ++nq) {
      float ls = l_[nq];
      ls += __shfl_xor(ls, 16);
      ls += __shfl_xor(ls, 32);
      lr[nq] = ls;
    }

    if (half == 1) {  // upper-half wave dumps partials (Obuf aliases staging)
#pragma unroll
      for (int nq = 0; nq < 2; ++nq) {
        if (quad == 0) lbuf[wl][nq][col] = lr[nq];
#pragma unroll
        for (int md = 0; md < 4; ++md)
          *(float4*)(Obuf + ((wl * 2 + nq) * 16 + col) * 68 + md * 16 + quad * 4) =
              (float4){ot[md][nq][0], ot[md][nq][1], ot[md][nq][2], ot[md][nq][3]};
      }
    }
    __syncthreads();

    if (half == 0) {  // lower-half wave merges (plain sums) and writes Om
#pragma unroll
      for (int nq = 0; nq < 2; ++nq) {
        const float inv = 1.0f / (lr[nq] + lbuf[wl][nq][col]);
        const int q = qbase + nq * 16 + col;
#pragma unroll
        for (int md = 0; md < 4; ++md) {
          const float4 ob =
              *(const float4*)(Obuf + ((wl * 2 + nq) * 16 + col) * 68 + md * 16 + quad * 4);
          uint2 pk;
          pk.x = bf16pair((ot[md][nq][0] + ob.x) * inv, (ot[md][nq][1] + ob.y) * inv);
          pk.y = bf16pair((ot[md][nq][2] + ob.z) * inv, (ot[md][nq][3] + ob.w) * inv);
          *(uint2*)(Om + (size_t)q * DMODEL + h * DHEAD + md * 16 + quad * 4) = pk;
        }
      }
    }
    __syncthreads();  // Obuf reads done before next pass re-stages over it
  }
}

extern "C" void kernel_launch(void* const* d_in, const int* in_sizes, int n_in,
                              void* d_out, int out_size, void* d_ws, size_t ws_size,
                              hipStream_t stream) {
  const float* x  = (const float*)d_in[0];
  const float* Wq = (const float*)d_in[2];
  const float* Wk = (const float*)d_in[3];
  const float* Wv = (const float*)d_in[4];
  const float* Wo = (const float*)d_in[5];
  float* out = (float*)d_out;

  const size_t M1 = (size_t)1 << 20;
  ushort_t* xb  = (ushort_t*)d_ws;      // bf16 x          4M elems
  ushort_t* Wb  = xb  + 4 * M1;         // bf16 Wq|Wk|Wv   3M (contiguous)
  ushort_t* wob = Wb  + 3 * M1;         // bf16 Wo         1M
  ushort_t* Qh  = wob + 1 * M1;         // bf16 [H][L][DH] 4M (pre-scaled C2)
  ushort_t* Kh  = Qh  + 4 * M1;         // bf16 [H][L][DH] 4M
  ushort_t* Vt  = Kh  + 4 * M1;         // bf16 [H][DH][L] 4M
  ushort_t* Om  = Vt  + 4 * M1;         // bf16 [L][D]     4M
  float2*   rope = (float2*)(Om + 4 * M1);  // 4096x32 float2, 1 MB

  rope_table<<<512, 256, 0, stream>>>(rope);
  cvt_bf16<<<8192, 256, 0, stream>>>(x, Wq, Wk, Wv, Wo, xb);
  mfma_gemm<1><<<dim3(3072 / 128, LSEQ / 128), 256, 0, stream>>>(
      Wb, xb, nullptr, rope, Qh, Kh, Vt);
  attn_mfma<<<dim3(NH, 16), 512, 0, stream>>>(Qh, Kh, Vt, Om);
  mfma_gemm<0><<<dim3(LSEQ / 128, DMODEL / 128), 256, 0, stream>>>(
      Om, wob, out, nullptr, nullptr, nullptr, nullptr);
}

// Round 12
// 269.544 us; speedup vs baseline: 19.6738x; 1.0404x over previous
//
#include <hip/hip_runtime.h>
#include <math.h>

#define LSEQ   4096
#define DMODEL 1024
#define NH     16
#define DHEAD  64
#define PSTRIDE 40  // P-buffer row stride in bf16: mult of 8 (b128 align)
// Finite mask: exp2(-30000) == 0 exactly; below-diagonal tiles contribute
// p=0, l=0, O=0 -> trivially correct under the sum-merge (no NaN path).
#define MASKV  -30000.0f
#define C2SCALE 0.18033688f  // 0.125 * log2(e), folded into Q projection

typedef __attribute__((ext_vector_type(8))) short  bf16x8;
typedef __attribute__((ext_vector_type(4))) float  floatx4;
typedef unsigned short ushort_t;

#if __has_builtin(__builtin_amdgcn_exp2f)
#define EXP2F __builtin_amdgcn_exp2f
#else
#define EXP2F exp2f
#endif

__device__ __forceinline__ ushort_t f2bf(float x) {
  unsigned u = __builtin_bit_cast(unsigned, x);
  return (ushort_t)((u + 0x7fff + ((u >> 16) & 1)) >> 16);
}
__device__ __forceinline__ unsigned bf16pair(float a, float b) {
  return (unsigned)f2bf(a) | ((unsigned)f2bf(b) << 16);
}
// truncating pack: low16 = hi16(a), high16 = hi16(b) — 1 VALU (v_perm_b32)
__device__ __forceinline__ unsigned bfpack_trunc(float a, float b) {
  return __builtin_amdgcn_perm(__builtin_bit_cast(unsigned, b),
                               __builtin_bit_cast(unsigned, a), 0x07060302u);
}
__device__ __forceinline__ void gl_lds16(const ushort_t* g, ushort_t* l) {
  __builtin_amdgcn_global_load_lds(
      (const __attribute__((address_space(1))) void*)g,
      (__attribute__((address_space(3))) void*)l, 16, 0, 0);
}

// ---------------------------------------------------------------------------
// Exact RoPE table: rope[s][t] = {cos(s*invf_t), sin(s*invf_t)}, 4096x32.
// ---------------------------------------------------------------------------
__global__ void rope_table(float2* __restrict__ rope) {
  const int idx = blockIdx.x * 256 + threadIdx.x;  // 131072 total
  const int s = idx >> 5, t = idx & 31;
  const double invf = exp((double)t * -0.28782313662425572);  // -ln(10000)/32
  const double ang = (double)s * invf;
  rope[idx] = make_float2((float)cos(ang), (float)sin(ang));
}

// ---------------------------------------------------------------------------
// fp32 -> bf16 for [x | Wq | Wk | Wv | Wo] into one contiguous buffer.
// ---------------------------------------------------------------------------
__global__ void cvt_bf16(const float* __restrict__ x,  const float* __restrict__ wq,
                         const float* __restrict__ wk, const float* __restrict__ wv,
                         const float* __restrict__ wo, ushort_t* __restrict__ dst) {
  const size_t e = ((size_t)blockIdx.x * 256 + threadIdx.x) * 4;  // elem idx, 8M total
  const float* src; size_t off;
  if      (e < (size_t)(4u << 20)) { src = x;  off = e; }
  else if (e < (size_t)(5u << 20)) { src = wq; off = e - (size_t)(4u << 20); }
  else if (e < (size_t)(6u << 20)) { src = wk; off = e - (size_t)(5u << 20); }
  else if (e < (size_t)(7u << 20)) { src = wv; off = e - (size_t)(6u << 20); }
  else                             { src = wo; off = e - (size_t)(7u << 20); }
  const float4 v = *(const float4*)(src + off);
  uint2 p; p.x = bf16pair(v.x, v.y); p.y = bf16pair(v.z, v.w);
  *(uint2*)(dst + e) = p;
}

// ---------------------------------------------------------------------------
// m97-style bf16 MFMA GEMM (unchanged from R8).
// MODE 0: A=Om(bf16), B=Wo(bf16) -> fp32 C row-major (final projection)
// MODE 1: A=W fused QKV rows (3072xK), B=x. RoPE / V^T epilogues.
//         Q outputs are pre-scaled by C2SCALE (softmax fold).
// ---------------------------------------------------------------------------
template<int MODE>
__global__ __launch_bounds__(256)
void mfma_gemm(const ushort_t* __restrict__ A, const ushort_t* __restrict__ B,
               float* __restrict__ C, const float2* __restrict__ rope,
               ushort_t* __restrict__ Qo, ushort_t* __restrict__ Ko,
               ushort_t* __restrict__ Vo) {
  __shared__ ushort_t As[128 * 64];
  __shared__ ushort_t Bs[128 * 64];
  const int tid  = threadIdx.x;
  const int w    = tid >> 6, lane = tid & 63;
  const int wm   = w >> 1,   wn   = w & 1;
  const int quad = lane >> 4, col = lane & 15;
  const int i0 = blockIdx.x * 128;
  const int j0 = blockIdx.y * 128;

  const ushort_t* Ab = A + (size_t)i0 * DMODEL;
  const ushort_t* Bb = B + (size_t)j0 * DMODEL;

  floatx4 acc[4][4];
#pragma unroll
  for (int mt = 0; mt < 4; ++mt)
#pragma unroll
    for (int nt = 0; nt < 4; ++nt) acc[mt][nt] = (floatx4){0.f, 0.f, 0.f, 0.f};

  const int lrow = lane >> 3;
  const int lcol = (lane & 7) * 8;

  for (int k0 = 0; k0 < DMODEL; k0 += 64) {
    __syncthreads();
#pragma unroll
    for (int it = 0; it < 4; ++it) {
      const int rb = (it * 4 + w) * 8;
      gl_lds16(Ab + (size_t)(rb + lrow) * DMODEL + k0 + lcol, As + rb * 64);
      gl_lds16(Bb + (size_t)(rb + lrow) * DMODEL + k0 + lcol, Bs + rb * 64);
    }
    __syncthreads();

#pragma unroll
    for (int kk = 0; kk < 64; kk += 32) {
      bf16x8 af[4], bfr[4];
#pragma unroll
      for (int mt = 0; mt < 4; ++mt)
        af[mt] = *(const bf16x8*)(As + (wm * 64 + mt * 16 + col) * 64 + kk + quad * 8);
#pragma unroll
      for (int nt = 0; nt < 4; ++nt)
        bfr[nt] = *(const bf16x8*)(Bs + (wn * 64 + nt * 16 + col) * 64 + kk + quad * 8);
#pragma unroll
      for (int mt = 0; mt < 4; ++mt)
#pragma unroll
        for (int nt = 0; nt < 4; ++nt)
          acc[mt][nt] = __builtin_amdgcn_mfma_f32_16x16x32_bf16(
              af[mt], bfr[nt], acc[mt][nt], 0, 0, 0);
    }
  }

  if (MODE == 0) {
#pragma unroll
    for (int mt = 0; mt < 4; ++mt) {
      const int i = i0 + wm * 64 + mt * 16 + quad * 4;
#pragma unroll
      for (int nt = 0; nt < 4; ++nt) {
        const int j = j0 + wn * 64 + nt * 16 + col;
#pragma unroll
        for (int r = 0; r < 4; ++r)
          C[(size_t)(i + r) * DMODEL + j] = acc[mt][nt][r];
      }
    }
  } else {
    const int which = i0 >> 10;               // 0=Q 1=K 2=V
#pragma unroll
    for (int mt = 0; mt < 4; ++mt) {
      const int f0 = i0 + wm * 64 + mt * 16 + quad * 4;
      const int h  = (f0 >> 6) & 15;
      const int d  = f0 & 63;
      if (which == 2) {
#pragma unroll
        for (int nt = 0; nt < 4; ++nt) {
          const int s = j0 + wn * 64 + nt * 16 + col;
#pragma unroll
          for (int r = 0; r < 4; ++r)
            Vo[(size_t)(h * DHEAD + d + r) * LSEQ + s] = f2bf(acc[mt][nt][r]);
        }
      } else {
        ushort_t* dst = which ? Ko : Qo;
        const float qs = which ? 1.0f : C2SCALE;  // fold softmax scale into Q
        const int t0 = d >> 1;
#pragma unroll
        for (int nt = 0; nt < 4; ++nt) {
          const int s = j0 + wn * 64 + nt * 16 + col;
          const float4 cst = *(const float4*)((const float*)rope + ((size_t)s << 6) + t0 * 2);
          ushort_t* ob = dst + ((size_t)h * LSEQ + s) * DHEAD;
          const float x1 = acc[mt][nt][0], x2 = acc[mt][nt][1];
          const float y1 = acc[mt][nt][2], y2 = acc[mt][nt][3];
          *(unsigned*)(ob + t0)      = bf16pair((x1 * cst.x - x2 * cst.y) * qs,
                                                (y1 * cst.z - y2 * cst.w) * qs);
          *(unsigned*)(ob + t0 + 32) = bf16pair((x1 * cst.y + x2 * cst.x) * qs,
                                                (y1 * cst.w + y2 * cst.z) * qs);
        }
      }
    }
  }
}

// ---------------------------------------------------------------------------
// MFMA flash attention v10 = v9 + XOR-swizzled K/V staging.
// R11 counters: SQ_LDS_BANK_CONFLICT 16.3M cy (~26 us/CU of the 86.5 us).
// Unpadded 64x64 tiles have 128 B rows -> kf/vf b128 reads hit ONE bank
// group across all 16 col-lanes (16-way conflict, ~5.7x per op, m136).
// global_load_lds forces LDS slot = base+lane*16, but the per-lane GLOBAL
// address is free: stage column-block cb^(r&7) into slot (r,cb) and apply
// the same XOR when reading -> banks spread to 2-way (free). Zero extra
// instructions on the read path (XOR folds into address calc).
// Everything else identical to R11.
// ---------------------------------------------------------------------------
__global__ __launch_bounds__(512, 2)
void attn_mfma(const ushort_t* __restrict__ Qh, const ushort_t* __restrict__ Kh,
               const ushort_t* __restrict__ Vt, ushort_t* __restrict__ Om) {
  const int h   = blockIdx.x;
  const int g   = blockIdx.y;
  const int tid = threadIdx.x;
  const int w    = tid >> 6;     // 0..7
  const int wl   = w & 3;        // q-unit slot (32 q rows each)
  const int half = w >> 2;       // 0 = keys [0,32) of each tile, 1 = [32,64)
  const int lane = tid & 63;
  const int quad = lane >> 4;
  const int col  = lane & 15;
  const int csw  = col & 7;      // row-derived swizzle key for reads

  // LDS map (bytes): Ks dbuf [0,16384) | Vs dbuf [16384,32768) |
  //                  P per-wave [32768,53248). Obuf (merge, 34816 B) aliases
  //                  the staging region after the key loop.
  __shared__ __align__(16) char smem[53248];
  ushort_t* Ks   = (ushort_t*)smem;                  // [2][64*64], swizzled
  ushort_t* Vs   = (ushort_t*)(smem + 16384);        // [2][64*64], swizzled
  ushort_t* Ps   = (ushort_t*)(smem + 32768);        // [8][32*PSTRIDE]
  float*    Obuf = (float*)smem;
  __shared__ float lbuf[4][2][16];
  ushort_t* psw = Ps + w * (32 * PSTRIDE);

  // staging lane geometry: wave w stages rows [w*8, w*8+8); lane's LDS slot
  // is (r = lane>>3, cblk = lane&7); it LOADS global column block
  // cblk ^ (r&7)  -> LDS holds tile[r][cb^(r&7)] at slot (r,cb).
  const int srow = w * 8 + (lane >> 3);
  const int scol = (((lane & 7) ^ ((lane >> 3) & 7)) * 8);

  for (int pass = 0; pass < 2; ++pass) {
    const int qb      = pass ? (31 - g) : g;
    const int qbase   = qb * 128 + wl * 32;
    const int nkt_max = 2 * qb + 2;   // uniform across all waves

    // Q B-frags (pre-scaled by C2), resident for the key loop
    bf16x8 qf[2][2];
#pragma unroll
    for (int nq = 0; nq < 2; ++nq)
#pragma unroll
      for (int c = 0; c < 2; ++c)
        qf[nq][c] = *(const bf16x8*)(Qh +
            ((size_t)(h * LSEQ + qbase + nq * 16 + col)) * DHEAD + quad * 8 + c * 32);

    floatx4 ot[4][2];
#pragma unroll
    for (int md = 0; md < 4; ++md)
#pragma unroll
      for (int nq = 0; nq < 2; ++nq) ot[md][nq] = (floatx4){0.f, 0.f, 0.f, 0.f};
    float l_[2] = {0.f, 0.f};

    // stage tile kt into LDS buffer b (wave-uniform bases; lane*16B dest)
    auto stage = [&](int kt, int b) {
      const int key0 = kt * 64;
      gl_lds16(Kh + ((size_t)(h * LSEQ + key0 + srow)) * DHEAD + scol,
               Ks + b * 4096 + w * 512);
      gl_lds16(Vt + ((size_t)(h * DHEAD + srow)) * LSEQ + key0 + scol,
               Vs + b * 4096 + w * 512);
    };

    stage(0, 0);
    __syncthreads();  // staging 0 visible (barrier drains vmcnt)

    for (int kt = 0; kt < nkt_max; ++kt) {
      const int buf = kt & 1;
      if (kt + 1 < nkt_max) stage(kt + 1, buf ^ 1);  // fills other buffer

      const ushort_t* kb = Ks + buf * 4096;
      const ushort_t* vb = Vs + buf * 4096;

      // kf frags from LDS (swizzled): row rk = half*32+mk*16+col, rk&7 = csw
      bf16x8 kf[2][2];
#pragma unroll
      for (int mk = 0; mk < 2; ++mk)
#pragma unroll
        for (int c = 0; c < 2; ++c)
          kf[mk][c] = *(const bf16x8*)(kb + (half * 32 + mk * 16 + col) * 64 +
                                       (((c * 4 + quad) ^ csw) * 8));

      // S^T = K . (C2*Q)^T  (32 keys x 32 q)
      floatx4 st[2][2];
#pragma unroll
      for (int mk = 0; mk < 2; ++mk)
#pragma unroll
        for (int nq = 0; nq < 2; ++nq) st[mk][nq] = (floatx4){0.f, 0.f, 0.f, 0.f};
#pragma unroll
      for (int mk = 0; mk < 2; ++mk)
#pragma unroll
        for (int c = 0; c < 2; ++c)
#pragma unroll
          for (int nq = 0; nq < 2; ++nq)
            st[mk][nq] = __builtin_amdgcn_mfma_f32_16x16x32_bf16(
                kf[mk][c], qf[nq][c], st[mk][nq], 0, 0, 0);

      // mask near/beyond the diagonal (absolute indices; below-diag = no-op,
      // beyond-diag tiles mask everything -> p=0)
      if (kt >= nkt_max - 2) {
        const int key0 = kt * 64 + half * 32;
#pragma unroll
        for (int mk = 0; mk < 2; ++mk) {
          const int keyb = key0 + mk * 16 + quad * 4;
#pragma unroll
          for (int nq = 0; nq < 2; ++nq) {
            const int q = qbase + nq * 16 + col;
#pragma unroll
            for (int r = 0; r < 4; ++r)
              if (keyb + r > q) st[mk][nq][r] = MASKV;
          }
        }
      }

      // p = exp2(S); accumulate l per-lane
#pragma unroll
      for (int mk = 0; mk < 2; ++mk)
#pragma unroll
        for (int nq = 0; nq < 2; ++nq) {
#pragma unroll
          for (int r = 0; r < 4; ++r) st[mk][nq][r] = EXP2F(st[mk][nq][r]);
          l_[nq] += (st[mk][nq][0] + st[mk][nq][1]) + (st[mk][nq][2] + st[mk][nq][3]);
        }

      // P^T -> per-wave LDS (truncating pack), then P B-frags
#pragma unroll
      for (int mk = 0; mk < 2; ++mk)
#pragma unroll
        for (int nq = 0; nq < 2; ++nq) {
          uint2 pk;
          pk.x = bfpack_trunc(st[mk][nq][0], st[mk][nq][1]);
          pk.y = bfpack_trunc(st[mk][nq][2], st[mk][nq][3]);
          *(uint2*)(psw + (nq * 16 + col) * PSTRIDE + mk * 16 + quad * 4) = pk;
        }
      bf16x8 pf[2];
#pragma unroll
      for (int nq = 0; nq < 2; ++nq)
        pf[nq] = *(const bf16x8*)(psw + (nq * 16 + col) * PSTRIDE + quad * 8);

      // vf frags from LDS (swizzled): row rv = md*16+col, rv&7 = csw
      bf16x8 vf[4];
#pragma unroll
      for (int md = 0; md < 4; ++md)
        vf[md] = *(const bf16x8*)(vb + (md * 16 + col) * 64 +
                                  (((half * 4 + quad) ^ csw) * 8));
#pragma unroll
      for (int md = 0; md < 4; ++md)
#pragma unroll
        for (int nq = 0; nq < 2; ++nq)
          ot[md][nq] = __builtin_amdgcn_mfma_f32_16x16x32_bf16(
              vf[md], pf[nq], ot[md][nq], 0, 0, 0);

      __syncthreads();  // staging kt+1 done; all reads of buf kt finished
    }

    // one-time l reduction per pass
    float lr[2];
#pragma unroll
    for (int nq = 0; nq < 2; ++nq) {
      float ls = l_[nq];
      ls += __shfl_xor(ls, 16);
      ls += __shfl_xor(ls, 32);
      lr[nq] = ls;
    }

    if (half == 1) {  // upper-half wave dumps partials (Obuf aliases staging)
#pragma unroll
      for (int nq = 0; nq < 2; ++nq) {
        if (quad == 0) lbuf[wl][nq][col] = lr[nq];
#pragma unroll
        for (int md = 0; md < 4; ++md)
          *(float4*)(Obuf + ((wl * 2 + nq) * 16 + col) * 68 + md * 16 + quad * 4) =
              (float4){ot[md][nq][0], ot[md][nq][1], ot[md][nq][2], ot[md][nq][3]};
      }
    }
    __syncthreads();

    if (half == 0) {  // lower-half wave merges (plain sums) and writes Om
#pragma unroll
      for (int nq = 0; nq < 2; ++nq) {
        const float inv = 1.0f / (lr[nq] + lbuf[wl][nq][col]);
        const int q = qbase + nq * 16 + col;
#pragma unroll
        for (int md = 0; md < 4; ++md) {
          const float4 ob =
              *(const float4*)(Obuf + ((wl * 2 + nq) * 16 + col) * 68 + md * 16 + quad * 4);
          uint2 pk;
          pk.x = bf16pair((ot[md][nq][0] + ob.x) * inv, (ot[md][nq][1] + ob.y) * inv);
          pk.y = bf16pair((ot[md][nq][2] + ob.z) * inv, (ot[md][nq][3] + ob.w) * inv);
          *(uint2*)(Om + (size_t)q * DMODEL + h * DHEAD + md * 16 + quad * 4) = pk;
        }
      }
    }
    __syncthreads();  // Obuf reads done before next pass re-stages over it
  }
}

extern "C" void kernel_launch(void* const* d_in, const int* in_sizes, int n_in,
                              void* d_out, int out_size, void* d_ws, size_t ws_size,
                              hipStream_t stream) {
  const float* x  = (const float*)d_in[0];
  const float* Wq = (const float*)d_in[2];
  const float* Wk = (const float*)d_in[3];
  const float* Wv = (const float*)d_in[4];
  const float* Wo = (const float*)d_in[5];
  float* out = (float*)d_out;

  const size_t M1 = (size_t)1 << 20;
  ushort_t* xb  = (ushort_t*)d_ws;      // bf16 x          4M elems
  ushort_t* Wb  = xb  + 4 * M1;         // bf16 Wq|Wk|Wv   3M (contiguous)
  ushort_t* wob = Wb  + 3 * M1;         // bf16 Wo         1M
  ushort_t* Qh  = wob + 1 * M1;         // bf16 [H][L][DH] 4M (pre-scaled C2)
  ushort_t* Kh  = Qh  + 4 * M1;         // bf16 [H][L][DH] 4M
  ushort_t* Vt  = Kh  + 4 * M1;         // bf16 [H][DH][L] 4M
  ushort_t* Om  = Vt  + 4 * M1;         // bf16 [L][D]     4M
  float2*   rope = (float2*)(Om + 4 * M1);  // 4096x32 float2, 1 MB

  rope_table<<<512, 256, 0, stream>>>(rope);
  cvt_bf16<<<8192, 256, 0, stream>>>(x, Wq, Wk, Wv, Wo, xb);
  mfma_gemm<1><<<dim3(3072 / 128, LSEQ / 128), 256, 0, stream>>>(
      Wb, xb, nullptr, rope, Qh, Kh, Vt);
  attn_mfma<<<dim3(NH, 16), 512, 0, stream>>>(Qh, Kh, Vt, Om);
  mfma_gemm<0><<<dim3(LSEQ / 128, DMODEL / 128), 256, 0, stream>>>(
      Om, wob, out, nullptr, nullptr, nullptr, nullptr);
}